// Round 5
// baseline (2639.004 us; speedup 1.0000x reference)
//
#include <hip/hip_runtime.h>
#include <hip/hip_bf16.h>

typedef __bf16 bf16;
typedef __attribute__((ext_vector_type(8))) __bf16 bf16x8;
typedef __attribute__((ext_vector_type(4))) __bf16 bf16x4;
typedef __attribute__((ext_vector_type(4))) float f32x4;

#define TOKENS 15360   // B*S = 16*960
#define HID    512
#define FFN_D  2048
#define QKV_D  1536

// ---------------------------------------------------------------------------
// fast exact-GELU: A&S 7.1.26 erf (|eps|<=1.5e-7), hw exp + hw rcp
// ---------------------------------------------------------------------------
__device__ __forceinline__ float gelu_erf(float x) {
  const float z = fabsf(x) * 0.70710678118654752f;
#if __has_builtin(__builtin_amdgcn_rcpf)
  const float t = __builtin_amdgcn_rcpf(fmaf(0.3275911f, z, 1.f));
#else
  const float t = 1.f / fmaf(0.3275911f, z, 1.f);
#endif
  float p = fmaf(1.061405429f, t, -1.453152027f);
  p = fmaf(p, t, 1.421413741f);
  p = fmaf(p, t, -0.284496736f);
  p = fmaf(p, t, 0.254829592f);
  p *= t;
  const float e  = __expf(-z * z);
  const float er = fmaf(-p, e, 1.f);          // erf(|x|/sqrt2)
  return 0.5f * x * (1.f + copysignf(er, x));
}

// ---------------------------------------------------------------------------
// fp32 -> bf16 weight conversion (run every launch; ws is re-poisoned)
// ---------------------------------------------------------------------------
__global__ __launch_bounds__(256) void cvt_kernel(const float* __restrict__ src,
                                                  bf16* __restrict__ dst, int n4) {
  const int i = (blockIdx.x * 256 + threadIdx.x);
  if (i >= n4) return;
  const float4 v = ((const float4*)src)[i];
  bf16x4 d = {(bf16)v.x, (bf16)v.y, (bf16)v.z, (bf16)v.w};
  *(bf16x4*)(dst + (size_t)i * 4) = d;
}

// ---------------------------------------------------------------------------
// GEMM: C[M,N] = A[M,K] @ W[N,K]^T (+bias fp32, + optional residual / GELU)
// 128x128 tile, BK=64, 4 waves, each 64x64 via 4x4 mfma_f32_16x16x32_bf16.
// SWAPPED operands: mfma(bfv, af) -> D layout m=lane&15, n=quad*4+reg, so a
// lane holds 4 CONSECUTIVE n-cols -> packed float4/bf16x4 epilogue I/O.
// L2 swizzle: 8 m-tiles x all n-tiles adjacent in dispatch order.
// NOTE (R4 lesson): do NOT hoist staging pointers into arrays — costs ~12
// VGPR and ~7% occupancy; compiler strength-reduces addresses anyway.
// ---------------------------------------------------------------------------
#define EPI_BIAS_BF16     0
#define EPI_BIAS_RES_F32  1
#define EPI_BIAS_GELU     2

template <int EPI>
__global__ __launch_bounds__(256) void gemm_bt(
    const bf16* __restrict__ A, const bf16* __restrict__ W,
    const float* __restrict__ bias, const bf16* __restrict__ R,
    void* __restrict__ out, int M, int N, int K) {
  __shared__ __align__(16) bf16 As[128 * 64];
  __shared__ __align__(16) bf16 Bs[128 * 64];

  const int tid  = threadIdx.x;
  const int lane = tid & 63;
  const int wv   = tid >> 6;
  const int li   = lane & 15;
  const int qd   = lane >> 4;
  const int mw   = (wv & 1) << 6;
  const int nw   = (wv >> 1) << 6;

  // L2 swizzle: groups of 8 m-tiles iterate all n-tiles first (MB % 8 == 0)
  const int NB  = gridDim.y;
  const int lin = blockIdx.y * gridDim.x + blockIdx.x;
  const int gid = lin / (8 * NB);
  const int rem = lin % (8 * NB);
  const int m0  = (gid * 8 + (rem & 7)) << 7;
  const int n0  = (rem >> 3) << 7;

  f32x4 acc[4][4];
#pragma unroll
  for (int i = 0; i < 4; ++i)
#pragma unroll
    for (int j = 0; j < 4; ++j) acc[i][j] = (f32x4){0.f, 0.f, 0.f, 0.f};

  const bf16* Abase = A + (size_t)m0 * K;
  const bf16* Wbase = W + (size_t)n0 * K;

  for (int k0 = 0; k0 < K; k0 += 64) {
#pragma unroll
    for (int it = 0; it < 4; ++it) {
      const int fc   = it * 256 + tid;       // chunk id: row r, slot c
      const int r    = fc >> 3;
      const int c    = fc & 7;
      const int koff = (c ^ (r & 7)) << 3;   // swizzled k-chunk
      const bf16* asrc = Abase + (size_t)r * K + k0 + koff;
      const bf16* bsrc = Wbase + (size_t)r * K + k0 + koff;
      bf16* adst = As + (size_t)(it * 256 + (tid & 192)) * 8;  // wave-uniform
      bf16* bdst = Bs + (size_t)(it * 256 + (tid & 192)) * 8;
      __builtin_amdgcn_global_load_lds(
          (const __attribute__((address_space(1))) unsigned int*)asrc,
          (__attribute__((address_space(3))) unsigned int*)adst, 16, 0, 0);
      __builtin_amdgcn_global_load_lds(
          (const __attribute__((address_space(1))) unsigned int*)bsrc,
          (__attribute__((address_space(3))) unsigned int*)bdst, 16, 0, 0);
    }
    __syncthreads();

#pragma unroll
    for (int ks = 0; ks < 2; ++ks) {
      const int ck = (ks << 2) + qd;         // A/B frag: k-chunk = quad (+4*ks)
      bf16x8 af[4], bfv[4];
#pragma unroll
      for (int i = 0; i < 4; ++i) {
        const int mr = mw + i * 16 + li;     // mr&7 == li&7
        af[i] = *(const bf16x8*)(As + mr * 64 + ((ck ^ (li & 7)) << 3));
      }
#pragma unroll
      for (int j = 0; j < 4; ++j) {
        const int nr = nw + j * 16 + li;
        bfv[j] = *(const bf16x8*)(Bs + nr * 64 + ((ck ^ (li & 7)) << 3));
      }
#pragma unroll
      for (int i = 0; i < 4; ++i)
#pragma unroll
        for (int j = 0; j < 4; ++j)
          acc[i][j] = __builtin_amdgcn_mfma_f32_16x16x32_bf16(bfv[j], af[i],
                                                              acc[i][j], 0, 0, 0);
    }
    __syncthreads();
  }

  // epilogue (swapped D): lane holds m-row (li) x 4 consecutive n-cols (qd*4+r)
#pragma unroll
  for (int i = 0; i < 4; ++i) {
    const int mrow = m0 + mw + i * 16 + li;
    const size_t rowoff = (size_t)mrow * N;
#pragma unroll
    for (int j = 0; j < 4; ++j) {
      const int ncol = n0 + nw + j * 16 + qd * 4;
      const float4 bv4 = *(const float4*)(bias + ncol);
      float v0 = acc[i][j][0] + bv4.x;
      float v1 = acc[i][j][1] + bv4.y;
      float v2 = acc[i][j][2] + bv4.z;
      float v3 = acc[i][j][3] + bv4.w;
      if (EPI == EPI_BIAS_RES_F32) {
        const bf16x4 r4 = *(const bf16x4*)(R + rowoff + ncol);
        float4 o = {v0 + (float)r4[0], v1 + (float)r4[1],
                    v2 + (float)r4[2], v3 + (float)r4[3]};
        *(float4*)((float*)out + rowoff + ncol) = o;
      } else if (EPI == EPI_BIAS_GELU) {
        bf16x4 o = {(bf16)gelu_erf(v0), (bf16)gelu_erf(v1),
                    (bf16)gelu_erf(v2), (bf16)gelu_erf(v3)};
        *(bf16x4*)((bf16*)out + rowoff + ncol) = o;
      } else {
        bf16x4 o = {(bf16)v0, (bf16)v1, (bf16)v2, (bf16)v3};
        *(bf16x4*)((bf16*)out + rowoff + ncol) = o;
      }
    }
  }
}

// ---------------------------------------------------------------------------
// MFMA attention: one block (4 waves) per (sequence, head).
// P padded to PP (16-mult) for tiles; K-dim of PV padded to PK (32-mult).
// ---------------------------------------------------------------------------
template <int P>
__global__ __launch_bounds__(256) void attn_kernel(const bf16* __restrict__ qkv,
                                                   bf16* __restrict__ out) {
  constexpr int PP   = ((P + 15) / 16) * 16;   // 32, 48, 96
  constexpr int PK   = ((PP + 31) / 32) * 32;  // 32, 64, 96
  constexpr int MT   = PP / 16;
  constexpr int SSTR = PP + 2;                 // fp32 words
  constexpr int VSTR = PK + 8;                 // bf16 elems; *2B is 16B-mult
  constexpr int PSTR = PK + 8;

  __shared__ __align__(16) bf16 QK[2 * PP * 64];  // Q | K ; reused as Ps
  __shared__ __align__(16) bf16 Vt[64 * VSTR];
  __shared__ __align__(16) float Sm[PP * SSTR];
  __shared__ float rsum[PP];

  bf16* Qs = QK;
  bf16* Ks = QK + PP * 64;
  bf16* Ps = QK;  // overlays Q/K after S phase (dead by then)

  const int tid  = threadIdx.x;
  const int lane = tid & 63;
  const int wv   = tid >> 6;
  const int li   = lane & 15;
  const int qd   = lane >> 4;
  const int n    = blockIdx.x >> 3;
  const int h    = blockIdx.x & 7;
  const bf16* base = qkv + (size_t)n * P * QKV_D + h * 64;

  // stage Q,K: 16B chunks, slot = c ^ (r&7)
  for (int t = tid; t < P * 8; t += 256) {
    const int r = t >> 3, c = t & 7;
    const bf16x8 qv = *(const bf16x8*)(base + (size_t)r * QKV_D + c * 8);
    const bf16x8 kv = *(const bf16x8*)(base + (size_t)r * QKV_D + 512 + c * 8);
    *(bf16x8*)(Qs + r * 64 + ((c ^ (r & 7)) * 8)) = qv;
    *(bf16x8*)(Ks + r * 64 + ((c ^ (r & 7)) * 8)) = kv;
  }
  // stage V^T
  for (int t = tid; t < P * 8; t += 256) {
    const int j = t % P, dc = t / P;
    const bf16x8 vv = *(const bf16x8*)(base + (size_t)j * QKV_D + 1024 + dc * 8);
#pragma unroll
    for (int u = 0; u < 8; ++u) Vt[(dc * 8 + u) * VSTR + j] = vv[u];
  }
  if constexpr (PK > P) {
    for (int t = tid; t < 64 * (PK - P); t += 256) {
      const int d = t / (PK - P), j = P + t % (PK - P);
      Vt[d * VSTR + j] = (bf16)0.f;
    }
  }
  __syncthreads();

  // S = Q K^T
  for (int t = wv; t < MT * MT; t += 4) {
    const int ti = t / MT, tj = t % MT;
    f32x4 acc = (f32x4){0.f, 0.f, 0.f, 0.f};
#pragma unroll
    for (int ks = 0; ks < 2; ++ks) {
      const int ck = ks * 4 + qd;
      const int ar = ti * 16 + li;
      const int br = tj * 16 + li;
      const bf16x8 af = *(const bf16x8*)(Qs + ar * 64 + ((ck ^ (ar & 7)) * 8));
      const bf16x8 bv = *(const bf16x8*)(Ks + br * 64 + ((ck ^ (br & 7)) * 8));
      acc = __builtin_amdgcn_mfma_f32_16x16x32_bf16(af, bv, acc, 0, 0, 0);
    }
#pragma unroll
    for (int r = 0; r < 4; ++r)
      Sm[(ti * 16 + qd * 4 + r) * SSTR + tj * 16 + li] = acc[r];
  }
  __syncthreads();

  // softmax row: unnormalized exp -> bf16 Ps; 1/sum saved for O-write
  if (tid < P) {
    const float* srow = Sm + tid * SSTR;
    bf16* prow = Ps + tid * PSTR;
    float mx = -1e30f;
    for (int j = 0; j < P; ++j) mx = fmaxf(mx, srow[j]);
    mx *= 0.125f;  // 1/sqrt(64)
    float sum = 0.f;
    for (int j = 0; j < P; ++j) {
      const float e = __expf(srow[j] * 0.125f - mx);
      sum += e;
      prow[j] = (bf16)e;
    }
    for (int j = P; j < PK; ++j) prow[j] = (bf16)0.f;
    rsum[tid] = 1.f / sum;
  }
  __syncthreads();

  // O = P V
  for (int t = wv; t < MT * 4; t += 4) {
    const int ti = t >> 2, td = t & 3;
    f32x4 acc = (f32x4){0.f, 0.f, 0.f, 0.f};
#pragma unroll
    for (int ks = 0; ks < PK / 32; ++ks) {
      const int ck = ks * 4 + qd;
      const bf16x8 af = *(const bf16x8*)(Ps + (ti * 16 + li) * PSTR + ck * 8);
      const bf16x8 bv = *(const bf16x8*)(Vt + (td * 16 + li) * VSTR + ck * 8);
      acc = __builtin_amdgcn_mfma_f32_16x16x32_bf16(af, bv, acc, 0, 0, 0);
    }
#pragma unroll
    for (int r = 0; r < 4; ++r) {
      const int row = ti * 16 + qd * 4 + r;
      if (row < P)
        out[(size_t)(n * P + row) * HID + h * 64 + td * 16 + li] =
            (bf16)(acc[r] * rsum[row]);
    }
  }
}

// ---------------------------------------------------------------------------
// LayerNorm over 512, one wave per row. float4 loads, bf16x4 stores.
// ---------------------------------------------------------------------------
__global__ __launch_bounds__(256) void ln_kernel(const float* __restrict__ Y,
                                                 const float* __restrict__ w,
                                                 const float* __restrict__ b,
                                                 bf16* __restrict__ X) {
  const int row  = blockIdx.x * 4 + (threadIdx.x >> 6);
  const int lane = threadIdx.x & 63;
  const float4* y4 = (const float4*)(Y + (size_t)row * HID);
  const float4 u = y4[lane];
  const float4 v = y4[lane + 64];
  float s  = u.x + u.y + u.z + u.w + v.x + v.y + v.z + v.w;
  float s2 = u.x*u.x + u.y*u.y + u.z*u.z + u.w*u.w +
             v.x*v.x + v.y*v.y + v.z*v.z + v.w*v.w;
#pragma unroll
  for (int off = 32; off > 0; off >>= 1) {
    s  += __shfl_xor(s, off, 64);
    s2 += __shfl_xor(s2, off, 64);
  }
  const float mean = s * (1.f / 512.f);
  const float var  = s2 * (1.f / 512.f) - mean * mean;
  const float rstd = rsqrtf(var + 1e-5f);
  const float4 w0 = ((const float4*)w)[lane];
  const float4 w1 = ((const float4*)w)[lane + 64];
  const float4 b0 = ((const float4*)b)[lane];
  const float4 b1 = ((const float4*)b)[lane + 64];
  bf16* xr = X + (size_t)row * HID;
  bf16x4 o0 = {(bf16)((u.x - mean) * rstd * w0.x + b0.x),
               (bf16)((u.y - mean) * rstd * w0.y + b0.y),
               (bf16)((u.z - mean) * rstd * w0.z + b0.z),
               (bf16)((u.w - mean) * rstd * w0.w + b0.w)};
  bf16x4 o1 = {(bf16)((v.x - mean) * rstd * w1.x + b1.x),
               (bf16)((v.y - mean) * rstd * w1.y + b1.y),
               (bf16)((v.z - mean) * rstd * w1.z + b1.z),
               (bf16)((v.w - mean) * rstd * w1.w + b1.w)};
  *(bf16x4*)(xr + 4 * lane)       = o0;
  *(bf16x4*)(xr + 256 + 4 * lane) = o1;
}

// ---------------------------------------------------------------------------
// input projection: h[r,o] = sum_k x[r,k]*w[o,k] + b[o], K=7. Writes the same
// value to nbr consecutive [TOKENS,HID] slices (branches share the input).
// ---------------------------------------------------------------------------
__global__ __launch_bounds__(256) void inproj_kernel(const float* __restrict__ x,
                                                     const float* __restrict__ w,
                                                     const float* __restrict__ b,
                                                     bf16* __restrict__ h,
                                                     int nbr) {
  const int idx = blockIdx.x * 256 + threadIdx.x;
  const int r = idx >> 9, o = idx & 511;
  float s = b[o];
#pragma unroll
  for (int k = 0; k < 7; ++k) s += x[r * 7 + k] * w[o * 7 + k];
  const bf16 bv = (bf16)s;
  for (int q = 0; q < nbr; ++q) h[idx + (size_t)q * TOKENS * HID] = bv;
}

// acc[row] (+)= X[row,:] . w  (per-branch final projection accumulate)
__global__ __launch_bounds__(256) void outdot_kernel(const bf16* __restrict__ X,
                                                     const float* __restrict__ w,
                                                     float* __restrict__ acc,
                                                     int first) {
  const int row  = blockIdx.x * 4 + (threadIdx.x >> 6);
  const int lane = threadIdx.x & 63;
  const bf16* xr = X + (size_t)row * HID;
  const bf16x8 xa = *(const bf16x8*)(xr + 8 * lane);
  const float4 wa = ((const float4*)w)[2 * lane];
  const float4 wb = ((const float4*)w)[2 * lane + 1];
  float s = (float)xa[0] * wa.x + (float)xa[1] * wa.y + (float)xa[2] * wa.z +
            (float)xa[3] * wa.w + (float)xa[4] * wb.x + (float)xa[5] * wb.y +
            (float)xa[6] * wb.z + (float)xa[7] * wb.w;
#pragma unroll
  for (int off = 32; off > 0; off >>= 1) s += __shfl_xor(s, off, 64);
  if (lane == 0) acc[row] = first ? s : (acc[row] + s);
}

// out[b,o] = (1/30) * sum_{j<10} acc[b*960 + o*10 + j] + b_out   (fp32 out)
__global__ __launch_bounds__(256) void pool_kernel(const float* __restrict__ acc,
                                                   const float* __restrict__ ob,
                                                   float* __restrict__ out) {
  const int idx = blockIdx.x * 256 + threadIdx.x;
  if (idx >= 16 * 96) return;
  const int bb = idx / 96, o = idx % 96;
  float s = 0.f;
#pragma unroll
  for (int j = 0; j < 10; ++j) s += acc[bb * 960 + o * 10 + j];
  out[idx] = s * (1.f / 30.f) + ob[0];
}

// ---------------------------------------------------------------------------
extern "C" void kernel_launch(void* const* d_in, const int* in_sizes, int n_in,
                              void* d_out, int out_size, void* d_ws,
                              size_t ws_size, hipStream_t stream) {
  const float* x          = (const float*)d_in[0];
  const float* ip_w       = (const float*)d_in[1];
  const float* ip_b       = (const float*)d_in[2];
  const float* in_proj_w  = (const float*)d_in[3];
  const float* in_proj_b  = (const float*)d_in[4];
  const float* out_proj_w = (const float*)d_in[5];
  const float* out_proj_b = (const float*)d_in[6];
  const float* ffn_w1     = (const float*)d_in[7];
  const float* ffn_b1     = (const float*)d_in[8];
  const float* ffn_w2     = (const float*)d_in[9];
  const float* ffn_b2     = (const float*)d_in[10];
  const float* ln1_w      = (const float*)d_in[11];
  const float* ln1_b      = (const float*)d_in[12];
  const float* ln2_w      = (const float*)d_in[13];
  const float* ln2_b      = (const float*)d_in[14];
  const float* op_w       = (const float*)d_in[15];
  const float* op_b       = (const float*)d_in[16];

  // fixed carve: weights + ACC, then activations (path-dependent)
  char* p = (char*)d_ws;
  bf16* Wq = (bf16*)p; p += (size_t)4 * QKV_D * HID * 2;
  bf16* Wo = (bf16*)p; p += (size_t)4 * HID * HID * 2;
  bf16* W1 = (bf16*)p; p += (size_t)4 * FFN_D * HID * 2;
  bf16* W2 = (bf16*)p; p += (size_t)4 * HID * FFN_D * 2;
  float* ACC = (float*)p; p += (size_t)TOKENS * 4;
  const size_t remain = ws_size - (size_t)(p - (char*)d_ws);

  const size_t T3 = 3 * (size_t)TOKENS;
  const size_t need_batched =
      T3 * HID * 4 + T3 * HID * 2 + T3 * FFN_D * 2;                // ~330 MB
  const size_t need_seq =
      (size_t)TOKENS * HID * 4 + (size_t)TOKENS * HID * 2 +
      (size_t)TOKENS * FFN_D * 2;                                  // ~110 MB
  const bool batched = remain >= need_batched;
  if (!batched && remain < need_seq) return;

  {  // weight conversion fp32 -> bf16
    const int nq = 4 * QKV_D * HID / 4, no = 4 * HID * HID / 4,
              n1 = 4 * FFN_D * HID / 4, n2 = 4 * HID * FFN_D / 4;
    cvt_kernel<<<(nq + 255) / 256, 256, 0, stream>>>(in_proj_w, Wq, nq);
    cvt_kernel<<<(no + 255) / 256, 256, 0, stream>>>(out_proj_w, Wo, no);
    cvt_kernel<<<(n1 + 255) / 256, 256, 0, stream>>>(ffn_w1, W1, n1);
    cvt_kernel<<<(n2 + 255) / 256, 256, 0, stream>>>(ffn_w2, W2, n2);
  }

  static const int periods[3] = {24, 48, 96};
  auto launch_attn = [&](int P, const bf16* q, bf16* o) {
    const int nblk = (TOKENS / P) * 8;
    if (P == 24)      attn_kernel<24><<<nblk, 256, 0, stream>>>(q, o);
    else if (P == 48) attn_kernel<48><<<nblk, 256, 0, stream>>>(q, o);
    else              attn_kernel<96><<<nblk, 256, 0, stream>>>(q, o);
  };

  if (batched) {
    float* Y  = (float*)p; p += T3 * HID * 4;
    bf16* X   = (bf16*)p;  p += T3 * HID * 2;
    bf16* SCR = (bf16*)p;  p += T3 * FFN_D * 2;
    bf16* ATT = SCR + T3 * QKV_D;  // tail of SCR
    const int M = (int)T3, MB = M / 128;

    inproj_kernel<<<TOKENS * HID / 256, 256, 0, stream>>>(x, ip_w, ip_b, X, 3);
    for (int l = 0; l < 4; ++l) {
      gemm_bt<EPI_BIAS_BF16><<<dim3(MB, QKV_D / 128), 256, 0, stream>>>(
          X, Wq + (size_t)l * QKV_D * HID, in_proj_b + l * QKV_D, nullptr,
          SCR, M, QKV_D, HID);
      for (int br = 0; br < 3; ++br)
        launch_attn(periods[br], SCR + (size_t)br * TOKENS * QKV_D,
                    ATT + (size_t)br * TOKENS * HID);
      gemm_bt<EPI_BIAS_RES_F32><<<dim3(MB, HID / 128), 256, 0, stream>>>(
          ATT, Wo + (size_t)l * HID * HID, out_proj_b + l * HID, X, Y,
          M, HID, HID);
      ln_kernel<<<M / 4, 256, 0, stream>>>(Y, ln1_w + l * HID, ln1_b + l * HID, X);
      gemm_bt<EPI_BIAS_GELU><<<dim3(MB, FFN_D / 128), 256, 0, stream>>>(
          X, W1 + (size_t)l * FFN_D * HID, ffn_b1 + l * FFN_D, nullptr,
          SCR, M, FFN_D, HID);
      gemm_bt<EPI_BIAS_RES_F32><<<dim3(MB, HID / 128), 256, 0, stream>>>(
          SCR, W2 + (size_t)l * HID * FFN_D, ffn_b2 + l * HID, X, Y,
          M, HID, FFN_D);
      ln_kernel<<<M / 4, 256, 0, stream>>>(Y, ln2_w + l * HID, ln2_b + l * HID, X);
    }
    for (int br = 0; br < 3; ++br)
      outdot_kernel<<<TOKENS / 4, 256, 0, stream>>>(
          X + (size_t)br * TOKENS * HID, op_w, ACC, br == 0);
  } else {
    // sequential (fits in ~135 MB)
    float* Y  = (float*)p; p += (size_t)TOKENS * HID * 4;
    bf16* X   = (bf16*)p;  p += (size_t)TOKENS * HID * 2;
    bf16* SCR = (bf16*)p;  p += (size_t)TOKENS * FFN_D * 2;
    bf16* ATT = SCR + (size_t)TOKENS * QKV_D;
    const int M = TOKENS, MB = M / 128;

    for (int br = 0; br < 3; ++br) {
      inproj_kernel<<<TOKENS * HID / 256, 256, 0, stream>>>(x, ip_w, ip_b, X, 1);
      for (int l = 0; l < 4; ++l) {
        gemm_bt<EPI_BIAS_BF16><<<dim3(MB, QKV_D / 128), 256, 0, stream>>>(
            X, Wq + (size_t)l * QKV_D * HID, in_proj_b + l * QKV_D, nullptr,
            SCR, M, QKV_D, HID);
        launch_attn(periods[br], SCR, ATT);
        gemm_bt<EPI_BIAS_RES_F32><<<dim3(MB, HID / 128), 256, 0, stream>>>(
            ATT, Wo + (size_t)l * HID * HID, out_proj_b + l * HID, X, Y,
            M, HID, HID);
        ln_kernel<<<M / 4, 256, 0, stream>>>(Y, ln1_w + l * HID,
                                             ln1_b + l * HID, X);
        gemm_bt<EPI_BIAS_GELU><<<dim3(MB, FFN_D / 128), 256, 0, stream>>>(
            X, W1 + (size_t)l * FFN_D * HID, ffn_b1 + l * FFN_D, nullptr,
            SCR, M, FFN_D, HID);
        gemm_bt<EPI_BIAS_RES_F32><<<dim3(MB, HID / 128), 256, 0, stream>>>(
            SCR, W2 + (size_t)l * HID * FFN_D, ffn_b2 + l * HID, X, Y,
            M, HID, FFN_D);
        ln_kernel<<<M / 4, 256, 0, stream>>>(Y, ln2_w + l * HID,
                                             ln2_b + l * HID, X);
      }
      outdot_kernel<<<TOKENS / 4, 256, 0, stream>>>(X, op_w, ACC, br == 0);
    }
  }
  pool_kernel<<<6, 256, 0, stream>>>(ACC, op_b, (float*)d_out);
}

// Round 6
// 2606.076 us; speedup vs baseline: 1.0126x; 1.0126x over previous
//
#include <hip/hip_runtime.h>
#include <hip/hip_bf16.h>

typedef __bf16 bf16;
typedef __attribute__((ext_vector_type(8))) __bf16 bf16x8;
typedef __attribute__((ext_vector_type(4))) __bf16 bf16x4;
typedef __attribute__((ext_vector_type(4))) float f32x4;

#define TOKENS 15360   // B*S = 16*960
#define HID    512
#define FFN_D  2048
#define QKV_D  1536

// ---------------------------------------------------------------------------
// fast exact-GELU: A&S 7.1.26 erf (|eps|<=1.5e-7), hw exp + hw rcp
// ---------------------------------------------------------------------------
__device__ __forceinline__ float gelu_erf(float x) {
  const float z = fabsf(x) * 0.70710678118654752f;
#if __has_builtin(__builtin_amdgcn_rcpf)
  const float t = __builtin_amdgcn_rcpf(fmaf(0.3275911f, z, 1.f));
#else
  const float t = 1.f / fmaf(0.3275911f, z, 1.f);
#endif
  float p = fmaf(1.061405429f, t, -1.453152027f);
  p = fmaf(p, t, 1.421413741f);
  p = fmaf(p, t, -0.284496736f);
  p = fmaf(p, t, 0.254829592f);
  p *= t;
  const float e  = __expf(-z * z);
  const float er = fmaf(-p, e, 1.f);          // erf(|x|/sqrt2)
  return 0.5f * x * (1.f + copysignf(er, x));
}

// ---------------------------------------------------------------------------
// fp32 -> bf16 weight conversion (run every launch; ws is re-poisoned)
// ---------------------------------------------------------------------------
__global__ __launch_bounds__(256) void cvt_kernel(const float* __restrict__ src,
                                                  bf16* __restrict__ dst, int n4) {
  const int i = (blockIdx.x * 256 + threadIdx.x);
  if (i >= n4) return;
  const float4 v = ((const float4*)src)[i];
  bf16x4 d = {(bf16)v.x, (bf16)v.y, (bf16)v.z, (bf16)v.w};
  *(bf16x4*)(dst + (size_t)i * 4) = d;
}

// ---------------------------------------------------------------------------
// GEMM: C[M,N] = A[M,K] @ W[N,K]^T (+bias fp32, + optional residual / GELU)
// 128x128 tile, BK=64, 4 waves, each 64x64 via 4x4 mfma_f32_16x16x32_bf16.
// SWAPPED operands: mfma(bfv, af) -> lane holds row=li x 4 consecutive n-cols
// (qd*4+reg) -> packed float4/bf16x4 epilogue I/O [R5: absmax-verified].
// R4 lesson: no staging-pointer hoist (costs VGPR > saves VALU).
// R5 lesson: no runtime-div L2 swizzle (VGPR 80->96, occupancy -8pt, net loss).
// __launch_bounds__(256,6): cap 85 VGPR — R3 proved this K-loop fits in 80;
// pins 6 waves/SIMD so epilogue convenience regs can't eat occupancy.
// ---------------------------------------------------------------------------
#define EPI_BIAS_BF16     0
#define EPI_BIAS_RES_F32  1
#define EPI_BIAS_GELU     2

template <int EPI>
__global__ __launch_bounds__(256, 6) void gemm_bt(
    const bf16* __restrict__ A, const bf16* __restrict__ W,
    const float* __restrict__ bias, const bf16* __restrict__ R,
    void* __restrict__ out, int M, int N, int K) {
  __shared__ __align__(16) bf16 As[128 * 64];
  __shared__ __align__(16) bf16 Bs[128 * 64];

  const int tid  = threadIdx.x;
  const int lane = tid & 63;
  const int wv   = tid >> 6;
  const int li   = lane & 15;
  const int qd   = lane >> 4;
  const int mw   = (wv & 1) << 6;
  const int nw   = (wv >> 1) << 6;
  const int m0   = blockIdx.x << 7;
  const int n0   = blockIdx.y << 7;

  f32x4 acc[4][4];
#pragma unroll
  for (int i = 0; i < 4; ++i)
#pragma unroll
    for (int j = 0; j < 4; ++j) acc[i][j] = (f32x4){0.f, 0.f, 0.f, 0.f};

  const bf16* Abase = A + (size_t)m0 * K;
  const bf16* Wbase = W + (size_t)n0 * K;

  for (int k0 = 0; k0 < K; k0 += 64) {
#pragma unroll
    for (int it = 0; it < 4; ++it) {
      const int fc   = it * 256 + tid;       // chunk id: row r, slot c
      const int r    = fc >> 3;
      const int c    = fc & 7;
      const int koff = (c ^ (r & 7)) << 3;   // swizzled k-chunk
      const bf16* asrc = Abase + (size_t)r * K + k0 + koff;
      const bf16* bsrc = Wbase + (size_t)r * K + k0 + koff;
      bf16* adst = As + (size_t)(it * 256 + (tid & 192)) * 8;  // wave-uniform
      bf16* bdst = Bs + (size_t)(it * 256 + (tid & 192)) * 8;
      __builtin_amdgcn_global_load_lds(
          (const __attribute__((address_space(1))) unsigned int*)asrc,
          (__attribute__((address_space(3))) unsigned int*)adst, 16, 0, 0);
      __builtin_amdgcn_global_load_lds(
          (const __attribute__((address_space(1))) unsigned int*)bsrc,
          (__attribute__((address_space(3))) unsigned int*)bdst, 16, 0, 0);
    }
    __syncthreads();

#pragma unroll
    for (int ks = 0; ks < 2; ++ks) {
      const int ck = (ks << 2) + qd;         // A/B frag: k-chunk = quad (+4*ks)
      bf16x8 af[4], bfv[4];
#pragma unroll
      for (int i = 0; i < 4; ++i) {
        const int mr = mw + i * 16 + li;     // mr&7 == li&7
        af[i] = *(const bf16x8*)(As + mr * 64 + ((ck ^ (li & 7)) << 3));
      }
#pragma unroll
      for (int j = 0; j < 4; ++j) {
        const int nr = nw + j * 16 + li;
        bfv[j] = *(const bf16x8*)(Bs + nr * 64 + ((ck ^ (li & 7)) << 3));
      }
#pragma unroll
      for (int i = 0; i < 4; ++i)
#pragma unroll
        for (int j = 0; j < 4; ++j)
          acc[i][j] = __builtin_amdgcn_mfma_f32_16x16x32_bf16(bfv[j], af[i],
                                                              acc[i][j], 0, 0, 0);
    }
    __syncthreads();
  }

  // epilogue (swapped D): lane holds m-row (li) x 4 consecutive n-cols (qd*4+r)
#pragma unroll
  for (int i = 0; i < 4; ++i) {
    const int mrow = m0 + mw + i * 16 + li;
    const size_t rowoff = (size_t)mrow * N;
#pragma unroll
    for (int j = 0; j < 4; ++j) {
      const int ncol = n0 + nw + j * 16 + qd * 4;
      const float4 bv4 = *(const float4*)(bias + ncol);
      float v0 = acc[i][j][0] + bv4.x;
      float v1 = acc[i][j][1] + bv4.y;
      float v2 = acc[i][j][2] + bv4.z;
      float v3 = acc[i][j][3] + bv4.w;
      if (EPI == EPI_BIAS_RES_F32) {
        const bf16x4 r4 = *(const bf16x4*)(R + rowoff + ncol);
        float4 o = {v0 + (float)r4[0], v1 + (float)r4[1],
                    v2 + (float)r4[2], v3 + (float)r4[3]};
        *(float4*)((float*)out + rowoff + ncol) = o;
      } else if (EPI == EPI_BIAS_GELU) {
        bf16x4 o = {(bf16)gelu_erf(v0), (bf16)gelu_erf(v1),
                    (bf16)gelu_erf(v2), (bf16)gelu_erf(v3)};
        *(bf16x4*)((bf16*)out + rowoff + ncol) = o;
      } else {
        bf16x4 o = {(bf16)v0, (bf16)v1, (bf16)v2, (bf16)v3};
        *(bf16x4*)((bf16*)out + rowoff + ncol) = o;
      }
    }
  }
}

// ---------------------------------------------------------------------------
// MFMA attention: one block (4 waves) per (sequence, head).
// P padded to PP (16-mult) for tiles; K-dim of PV padded to PK (32-mult).
// ---------------------------------------------------------------------------
template <int P>
__global__ __launch_bounds__(256) void attn_kernel(const bf16* __restrict__ qkv,
                                                   bf16* __restrict__ out) {
  constexpr int PP   = ((P + 15) / 16) * 16;   // 32, 48, 96
  constexpr int PK   = ((PP + 31) / 32) * 32;  // 32, 64, 96
  constexpr int MT   = PP / 16;
  constexpr int SSTR = PP + 2;                 // fp32 words
  constexpr int VSTR = PK + 8;                 // bf16 elems; *2B is 16B-mult
  constexpr int PSTR = PK + 8;

  __shared__ __align__(16) bf16 QK[2 * PP * 64];  // Q | K ; reused as Ps
  __shared__ __align__(16) bf16 Vt[64 * VSTR];
  __shared__ __align__(16) float Sm[PP * SSTR];
  __shared__ float rsum[PP];

  bf16* Qs = QK;
  bf16* Ks = QK + PP * 64;
  bf16* Ps = QK;  // overlays Q/K after S phase (dead by then)

  const int tid  = threadIdx.x;
  const int lane = tid & 63;
  const int wv   = tid >> 6;
  const int li   = lane & 15;
  const int qd   = lane >> 4;
  const int n    = blockIdx.x >> 3;
  const int h    = blockIdx.x & 7;
  const bf16* base = qkv + (size_t)n * P * QKV_D + h * 64;

  // stage Q,K: 16B chunks, slot = c ^ (r&7)
  for (int t = tid; t < P * 8; t += 256) {
    const int r = t >> 3, c = t & 7;
    const bf16x8 qv = *(const bf16x8*)(base + (size_t)r * QKV_D + c * 8);
    const bf16x8 kv = *(const bf16x8*)(base + (size_t)r * QKV_D + 512 + c * 8);
    *(bf16x8*)(Qs + r * 64 + ((c ^ (r & 7)) * 8)) = qv;
    *(bf16x8*)(Ks + r * 64 + ((c ^ (r & 7)) * 8)) = kv;
  }
  // stage V^T
  for (int t = tid; t < P * 8; t += 256) {
    const int j = t % P, dc = t / P;
    const bf16x8 vv = *(const bf16x8*)(base + (size_t)j * QKV_D + 1024 + dc * 8);
#pragma unroll
    for (int u = 0; u < 8; ++u) Vt[(dc * 8 + u) * VSTR + j] = vv[u];
  }
  if constexpr (PK > P) {
    for (int t = tid; t < 64 * (PK - P); t += 256) {
      const int d = t / (PK - P), j = P + t % (PK - P);
      Vt[d * VSTR + j] = (bf16)0.f;
    }
  }
  __syncthreads();

  // S = Q K^T
  for (int t = wv; t < MT * MT; t += 4) {
    const int ti = t / MT, tj = t % MT;
    f32x4 acc = (f32x4){0.f, 0.f, 0.f, 0.f};
#pragma unroll
    for (int ks = 0; ks < 2; ++ks) {
      const int ck = ks * 4 + qd;
      const int ar = ti * 16 + li;
      const int br = tj * 16 + li;
      const bf16x8 af = *(const bf16x8*)(Qs + ar * 64 + ((ck ^ (ar & 7)) * 8));
      const bf16x8 bv = *(const bf16x8*)(Ks + br * 64 + ((ck ^ (br & 7)) * 8));
      acc = __builtin_amdgcn_mfma_f32_16x16x32_bf16(af, bv, acc, 0, 0, 0);
    }
#pragma unroll
    for (int r = 0; r < 4; ++r)
      Sm[(ti * 16 + qd * 4 + r) * SSTR + tj * 16 + li] = acc[r];
  }
  __syncthreads();

  // softmax row: unnormalized exp -> bf16 Ps; 1/sum saved for O-write
  if (tid < P) {
    const float* srow = Sm + tid * SSTR;
    bf16* prow = Ps + tid * PSTR;
    float mx = -1e30f;
    for (int j = 0; j < P; ++j) mx = fmaxf(mx, srow[j]);
    mx *= 0.125f;  // 1/sqrt(64)
    float sum = 0.f;
    for (int j = 0; j < P; ++j) {
      const float e = __expf(srow[j] * 0.125f - mx);
      sum += e;
      prow[j] = (bf16)e;
    }
    for (int j = P; j < PK; ++j) prow[j] = (bf16)0.f;
    rsum[tid] = 1.f / sum;
  }
  __syncthreads();

  // O = P V
  for (int t = wv; t < MT * 4; t += 4) {
    const int ti = t >> 2, td = t & 3;
    f32x4 acc = (f32x4){0.f, 0.f, 0.f, 0.f};
#pragma unroll
    for (int ks = 0; ks < PK / 32; ++ks) {
      const int ck = ks * 4 + qd;
      const bf16x8 af = *(const bf16x8*)(Ps + (ti * 16 + li) * PSTR + ck * 8);
      const bf16x8 bv = *(const bf16x8*)(Vt + (td * 16 + li) * VSTR + ck * 8);
      acc = __builtin_amdgcn_mfma_f32_16x16x32_bf16(af, bv, acc, 0, 0, 0);
    }
#pragma unroll
    for (int r = 0; r < 4; ++r) {
      const int row = ti * 16 + qd * 4 + r;
      if (row < P)
        out[(size_t)(n * P + row) * HID + h * 64 + td * 16 + li] =
            (bf16)(acc[r] * rsum[row]);
    }
  }
}

// ---------------------------------------------------------------------------
// LayerNorm over 512, one wave per row. float4 loads, bf16x4 stores.
// ---------------------------------------------------------------------------
__global__ __launch_bounds__(256) void ln_kernel(const float* __restrict__ Y,
                                                 const float* __restrict__ w,
                                                 const float* __restrict__ b,
                                                 bf16* __restrict__ X) {
  const int row  = blockIdx.x * 4 + (threadIdx.x >> 6);
  const int lane = threadIdx.x & 63;
  const float4* y4 = (const float4*)(Y + (size_t)row * HID);
  const float4 u = y4[lane];
  const float4 v = y4[lane + 64];
  float s  = u.x + u.y + u.z + u.w + v.x + v.y + v.z + v.w;
  float s2 = u.x*u.x + u.y*u.y + u.z*u.z + u.w*u.w +
             v.x*v.x + v.y*v.y + v.z*v.z + v.w*v.w;
#pragma unroll
  for (int off = 32; off > 0; off >>= 1) {
    s  += __shfl_xor(s, off, 64);
    s2 += __shfl_xor(s2, off, 64);
  }
  const float mean = s * (1.f / 512.f);
  const float var  = s2 * (1.f / 512.f) - mean * mean;
  const float rstd = rsqrtf(var + 1e-5f);
  const float4 w0 = ((const float4*)w)[lane];
  const float4 w1 = ((const float4*)w)[lane + 64];
  const float4 b0 = ((const float4*)b)[lane];
  const float4 b1 = ((const float4*)b)[lane + 64];
  bf16* xr = X + (size_t)row * HID;
  bf16x4 o0 = {(bf16)((u.x - mean) * rstd * w0.x + b0.x),
               (bf16)((u.y - mean) * rstd * w0.y + b0.y),
               (bf16)((u.z - mean) * rstd * w0.z + b0.z),
               (bf16)((u.w - mean) * rstd * w0.w + b0.w)};
  bf16x4 o1 = {(bf16)((v.x - mean) * rstd * w1.x + b1.x),
               (bf16)((v.y - mean) * rstd * w1.y + b1.y),
               (bf16)((v.z - mean) * rstd * w1.z + b1.z),
               (bf16)((v.w - mean) * rstd * w1.w + b1.w)};
  *(bf16x4*)(xr + 4 * lane)       = o0;
  *(bf16x4*)(xr + 256 + 4 * lane) = o1;
}

// ---------------------------------------------------------------------------
// input projection: h[r,o] = sum_k x[r,k]*w[o,k] + b[o], K=7. Writes the same
// value to nbr consecutive [TOKENS,HID] slices (branches share the input).
// ---------------------------------------------------------------------------
__global__ __launch_bounds__(256) void inproj_kernel(const float* __restrict__ x,
                                                     const float* __restrict__ w,
                                                     const float* __restrict__ b,
                                                     bf16* __restrict__ h,
                                                     int nbr) {
  const int idx = blockIdx.x * 256 + threadIdx.x;
  const int r = idx >> 9, o = idx & 511;
  float s = b[o];
#pragma unroll
  for (int k = 0; k < 7; ++k) s += x[r * 7 + k] * w[o * 7 + k];
  const bf16 bv = (bf16)s;
  for (int q = 0; q < nbr; ++q) h[idx + (size_t)q * TOKENS * HID] = bv;
}

// acc[row] (+)= X[row,:] . w  (per-branch final projection accumulate)
__global__ __launch_bounds__(256) void outdot_kernel(const bf16* __restrict__ X,
                                                     const float* __restrict__ w,
                                                     float* __restrict__ acc,
                                                     int first) {
  const int row  = blockIdx.x * 4 + (threadIdx.x >> 6);
  const int lane = threadIdx.x & 63;
  const bf16* xr = X + (size_t)row * HID;
  const bf16x8 xa = *(const bf16x8*)(xr + 8 * lane);
  const float4 wa = ((const float4*)w)[2 * lane];
  const float4 wb = ((const float4*)w)[2 * lane + 1];
  float s = (float)xa[0] * wa.x + (float)xa[1] * wa.y + (float)xa[2] * wa.z +
            (float)xa[3] * wa.w + (float)xa[4] * wb.x + (float)xa[5] * wb.y +
            (float)xa[6] * wb.z + (float)xa[7] * wb.w;
#pragma unroll
  for (int off = 32; off > 0; off >>= 1) s += __shfl_xor(s, off, 64);
  if (lane == 0) acc[row] = first ? s : (acc[row] + s);
}

// out[b,o] = (1/30) * sum_{j<10} acc[b*960 + o*10 + j] + b_out   (fp32 out)
__global__ __launch_bounds__(256) void pool_kernel(const float* __restrict__ acc,
                                                   const float* __restrict__ ob,
                                                   float* __restrict__ out) {
  const int idx = blockIdx.x * 256 + threadIdx.x;
  if (idx >= 16 * 96) return;
  const int bb = idx / 96, o = idx % 96;
  float s = 0.f;
#pragma unroll
  for (int j = 0; j < 10; ++j) s += acc[bb * 960 + o * 10 + j];
  out[idx] = s * (1.f / 30.f) + ob[0];
}

// ---------------------------------------------------------------------------
extern "C" void kernel_launch(void* const* d_in, const int* in_sizes, int n_in,
                              void* d_out, int out_size, void* d_ws,
                              size_t ws_size, hipStream_t stream) {
  const float* x          = (const float*)d_in[0];
  const float* ip_w       = (const float*)d_in[1];
  const float* ip_b       = (const float*)d_in[2];
  const float* in_proj_w  = (const float*)d_in[3];
  const float* in_proj_b  = (const float*)d_in[4];
  const float* out_proj_w = (const float*)d_in[5];
  const float* out_proj_b = (const float*)d_in[6];
  const float* ffn_w1     = (const float*)d_in[7];
  const float* ffn_b1     = (const float*)d_in[8];
  const float* ffn_w2     = (const float*)d_in[9];
  const float* ffn_b2     = (const float*)d_in[10];
  const float* ln1_w      = (const float*)d_in[11];
  const float* ln1_b      = (const float*)d_in[12];
  const float* ln2_w      = (const float*)d_in[13];
  const float* ln2_b      = (const float*)d_in[14];
  const float* op_w       = (const float*)d_in[15];
  const float* op_b       = (const float*)d_in[16];

  // fixed carve: weights + ACC, then activations (path-dependent)
  char* p = (char*)d_ws;
  bf16* Wq = (bf16*)p; p += (size_t)4 * QKV_D * HID * 2;
  bf16* Wo = (bf16*)p; p += (size_t)4 * HID * HID * 2;
  bf16* W1 = (bf16*)p; p += (size_t)4 * FFN_D * HID * 2;
  bf16* W2 = (bf16*)p; p += (size_t)4 * HID * FFN_D * 2;
  float* ACC = (float*)p; p += (size_t)TOKENS * 4;
  const size_t remain = ws_size - (size_t)(p - (char*)d_ws);

  const size_t T3 = 3 * (size_t)TOKENS;
  const size_t need_batched =
      T3 * HID * 4 + T3 * HID * 2 + T3 * FFN_D * 2;                // ~330 MB
  const size_t need_seq =
      (size_t)TOKENS * HID * 4 + (size_t)TOKENS * HID * 2 +
      (size_t)TOKENS * FFN_D * 2;                                  // ~110 MB
  const bool batched = remain >= need_batched;
  if (!batched && remain < need_seq) return;

  {  // weight conversion fp32 -> bf16
    const int nq = 4 * QKV_D * HID / 4, no = 4 * HID * HID / 4,
              n1 = 4 * FFN_D * HID / 4, n2 = 4 * HID * FFN_D / 4;
    cvt_kernel<<<(nq + 255) / 256, 256, 0, stream>>>(in_proj_w, Wq, nq);
    cvt_kernel<<<(no + 255) / 256, 256, 0, stream>>>(out_proj_w, Wo, no);
    cvt_kernel<<<(n1 + 255) / 256, 256, 0, stream>>>(ffn_w1, W1, n1);
    cvt_kernel<<<(n2 + 255) / 256, 256, 0, stream>>>(ffn_w2, W2, n2);
  }

  static const int periods[3] = {24, 48, 96};
  auto launch_attn = [&](int P, const bf16* q, bf16* o) {
    const int nblk = (TOKENS / P) * 8;
    if (P == 24)      attn_kernel<24><<<nblk, 256, 0, stream>>>(q, o);
    else if (P == 48) attn_kernel<48><<<nblk, 256, 0, stream>>>(q, o);
    else              attn_kernel<96><<<nblk, 256, 0, stream>>>(q, o);
  };

  if (batched) {
    float* Y  = (float*)p; p += T3 * HID * 4;
    bf16* X   = (bf16*)p;  p += T3 * HID * 2;
    bf16* SCR = (bf16*)p;  p += T3 * FFN_D * 2;
    bf16* ATT = SCR + T3 * QKV_D;  // tail of SCR
    const int M = (int)T3, MB = M / 128;

    inproj_kernel<<<TOKENS * HID / 256, 256, 0, stream>>>(x, ip_w, ip_b, X, 3);
    for (int l = 0; l < 4; ++l) {
      gemm_bt<EPI_BIAS_BF16><<<dim3(MB, QKV_D / 128), 256, 0, stream>>>(
          X, Wq + (size_t)l * QKV_D * HID, in_proj_b + l * QKV_D, nullptr,
          SCR, M, QKV_D, HID);
      for (int br = 0; br < 3; ++br)
        launch_attn(periods[br], SCR + (size_t)br * TOKENS * QKV_D,
                    ATT + (size_t)br * TOKENS * HID);
      gemm_bt<EPI_BIAS_RES_F32><<<dim3(MB, HID / 128), 256, 0, stream>>>(
          ATT, Wo + (size_t)l * HID * HID, out_proj_b + l * HID, X, Y,
          M, HID, HID);
      ln_kernel<<<M / 4, 256, 0, stream>>>(Y, ln1_w + l * HID, ln1_b + l * HID, X);
      gemm_bt<EPI_BIAS_GELU><<<dim3(MB, FFN_D / 128), 256, 0, stream>>>(
          X, W1 + (size_t)l * FFN_D * HID, ffn_b1 + l * FFN_D, nullptr,
          SCR, M, FFN_D, HID);
      gemm_bt<EPI_BIAS_RES_F32><<<dim3(MB, HID / 128), 256, 0, stream>>>(
          SCR, W2 + (size_t)l * HID * FFN_D, ffn_b2 + l * HID, X, Y,
          M, HID, FFN_D);
      ln_kernel<<<M / 4, 256, 0, stream>>>(Y, ln2_w + l * HID, ln2_b + l * HID, X);
    }
    for (int br = 0; br < 3; ++br)
      outdot_kernel<<<TOKENS / 4, 256, 0, stream>>>(
          X + (size_t)br * TOKENS * HID, op_w, ACC, br == 0);
  } else {
    // sequential (fits in ~135 MB)
    float* Y  = (float*)p; p += (size_t)TOKENS * HID * 4;
    bf16* X   = (bf16*)p;  p += (size_t)TOKENS * HID * 2;
    bf16* SCR = (bf16*)p;  p += (size_t)TOKENS * FFN_D * 2;
    bf16* ATT = SCR + (size_t)TOKENS * QKV_D;
    const int M = TOKENS, MB = M / 128;

    for (int br = 0; br < 3; ++br) {
      inproj_kernel<<<TOKENS * HID / 256, 256, 0, stream>>>(x, ip_w, ip_b, X, 1);
      for (int l = 0; l < 4; ++l) {
        gemm_bt<EPI_BIAS_BF16><<<dim3(MB, QKV_D / 128), 256, 0, stream>>>(
            X, Wq + (size_t)l * QKV_D * HID, in_proj_b + l * QKV_D, nullptr,
            SCR, M, QKV_D, HID);
        launch_attn(periods[br], SCR, ATT);
        gemm_bt<EPI_BIAS_RES_F32><<<dim3(MB, HID / 128), 256, 0, stream>>>(
            ATT, Wo + (size_t)l * HID * HID, out_proj_b + l * HID, X, Y,
            M, HID, HID);
        ln_kernel<<<M / 4, 256, 0, stream>>>(Y, ln1_w + l * HID,
                                             ln1_b + l * HID, X);
        gemm_bt<EPI_BIAS_GELU><<<dim3(MB, FFN_D / 128), 256, 0, stream>>>(
            X, W1 + (size_t)l * FFN_D * HID, ffn_b1 + l * FFN_D, nullptr,
            SCR, M, FFN_D, HID);
        gemm_bt<EPI_BIAS_RES_F32><<<dim3(MB, HID / 128), 256, 0, stream>>>(
            SCR, W2 + (size_t)l * HID * FFN_D, ffn_b2 + l * HID, X, Y,
            M, HID, FFN_D);
        ln_kernel<<<M / 4, 256, 0, stream>>>(Y, ln2_w + l * HID,
                                             ln2_b + l * HID, X);
      }
      outdot_kernel<<<TOKENS / 4, 256, 0, stream>>>(X, op_w, ACC, br == 0);
    }
  }
  pool_kernel<<<6, 256, 0, stream>>>(ACC, op_b, (float*)d_out);
}

// Round 7
// 2471.706 us; speedup vs baseline: 1.0677x; 1.0544x over previous
//
#include <hip/hip_runtime.h>
#include <hip/hip_bf16.h>

typedef __bf16 bf16;
typedef __attribute__((ext_vector_type(8))) __bf16 bf16x8;
typedef __attribute__((ext_vector_type(4))) __bf16 bf16x4;
typedef __attribute__((ext_vector_type(4))) float f32x4;

#define TOKENS 15360   // B*S = 16*960
#define HID    512
#define FFN_D  2048
#define QKV_D  1536

// ---------------------------------------------------------------------------
// fast exact-GELU: A&S 7.1.26 erf (|eps|<=1.5e-7), hw exp + hw rcp
// ---------------------------------------------------------------------------
__device__ __forceinline__ float gelu_erf(float x) {
  const float z = fabsf(x) * 0.70710678118654752f;
#if __has_builtin(__builtin_amdgcn_rcpf)
  const float t = __builtin_amdgcn_rcpf(fmaf(0.3275911f, z, 1.f));
#else
  const float t = 1.f / fmaf(0.3275911f, z, 1.f);
#endif
  float p = fmaf(1.061405429f, t, -1.453152027f);
  p = fmaf(p, t, 1.421413741f);
  p = fmaf(p, t, -0.284496736f);
  p = fmaf(p, t, 0.254829592f);
  p *= t;
  const float e  = __expf(-z * z);
  const float er = fmaf(-p, e, 1.f);          // erf(|x|/sqrt2)
  return 0.5f * x * (1.f + copysignf(er, x));
}

// ---------------------------------------------------------------------------
// fp32 -> bf16 weight conversion (run every launch; ws is re-poisoned)
// ---------------------------------------------------------------------------
__global__ __launch_bounds__(256) void cvt_kernel(const float* __restrict__ src,
                                                  bf16* __restrict__ dst, int n4) {
  const int i = (blockIdx.x * 256 + threadIdx.x);
  if (i >= n4) return;
  const float4 v = ((const float4*)src)[i];
  bf16x4 d = {(bf16)v.x, (bf16)v.y, (bf16)v.z, (bf16)v.w};
  *(bf16x4*)(dst + (size_t)i * 4) = d;
}

// ---------------------------------------------------------------------------
// GEMM: C[M,N] = A[M,K] @ W[N,K]^T (+bias fp32, + optional residual / GELU)
// 128x128 tile, BK=64, 4 waves, each 64x64 via 4x4 mfma_f32_16x16x32_bf16.
// EXACT R3 structure (measured best: 80 VGPR, 64 us FFN1, 503 TF):
//  - in-loop staging address calc (R4 lesson: hoisting costs VGPR > VALU)
//  - normal operand order + scalar epilogue (R5/R6 lesson: packed/swapped
//    epilogue raises VGPR 80->96, occupancy -8pt, net loss)
//  - no min-waves launch bound (R6: it failed to cap VGPR anyway)
// K-loop is LDS-read-throughput-bound (~16KB frags/wave/iter vs 155 MFMA
// cyc/SIMD) -> epilogue micro-opt cannot move it.
// RES epilogue writes the residual sum as bf16 (halves write traffic).
// ---------------------------------------------------------------------------
#define EPI_BIAS_BF16     0
#define EPI_BIAS_RES      1
#define EPI_BIAS_GELU     2

template <int EPI>
__global__ __launch_bounds__(256) void gemm_bt(
    const bf16* __restrict__ A, const bf16* __restrict__ W,
    const float* __restrict__ bias, const bf16* __restrict__ R,
    bf16* __restrict__ out, int M, int N, int K) {
  __shared__ __align__(16) bf16 As[128 * 64];
  __shared__ __align__(16) bf16 Bs[128 * 64];

  const int tid  = threadIdx.x;
  const int lane = tid & 63;
  const int wv   = tid >> 6;
  const int li   = lane & 15;
  const int qd   = lane >> 4;
  const int mw   = (wv & 1) << 6;
  const int nw   = (wv >> 1) << 6;
  const int m0   = blockIdx.x << 7;
  const int n0   = blockIdx.y << 7;

  f32x4 acc[4][4];
#pragma unroll
  for (int i = 0; i < 4; ++i)
#pragma unroll
    for (int j = 0; j < 4; ++j) acc[i][j] = (f32x4){0.f, 0.f, 0.f, 0.f};

  const bf16* Abase = A + (size_t)m0 * K;
  const bf16* Wbase = W + (size_t)n0 * K;

  for (int k0 = 0; k0 < K; k0 += 64) {
#pragma unroll
    for (int it = 0; it < 4; ++it) {
      const int fc   = it * 256 + tid;       // chunk id: row r, slot c
      const int r    = fc >> 3;
      const int c    = fc & 7;
      const int koff = (c ^ (r & 7)) << 3;   // swizzled k-chunk
      const bf16* asrc = Abase + (size_t)r * K + k0 + koff;
      const bf16* bsrc = Wbase + (size_t)r * K + k0 + koff;
      bf16* adst = As + (size_t)(it * 256 + (tid & 192)) * 8;  // wave-uniform
      bf16* bdst = Bs + (size_t)(it * 256 + (tid & 192)) * 8;
      __builtin_amdgcn_global_load_lds(
          (const __attribute__((address_space(1))) unsigned int*)asrc,
          (__attribute__((address_space(3))) unsigned int*)adst, 16, 0, 0);
      __builtin_amdgcn_global_load_lds(
          (const __attribute__((address_space(1))) unsigned int*)bsrc,
          (__attribute__((address_space(3))) unsigned int*)bdst, 16, 0, 0);
    }
    __syncthreads();

#pragma unroll
    for (int ks = 0; ks < 2; ++ks) {
      const int ck = (ks << 2) + qd;         // A/B frag: k-chunk = quad (+4*ks)
      bf16x8 af[4], bfv[4];
#pragma unroll
      for (int i = 0; i < 4; ++i) {
        const int mr = mw + i * 16 + li;     // mr&7 == li&7
        af[i] = *(const bf16x8*)(As + mr * 64 + ((ck ^ (li & 7)) << 3));
      }
#pragma unroll
      for (int j = 0; j < 4; ++j) {
        const int nr = nw + j * 16 + li;
        bfv[j] = *(const bf16x8*)(Bs + nr * 64 + ((ck ^ (li & 7)) << 3));
      }
#pragma unroll
      for (int i = 0; i < 4; ++i)
#pragma unroll
        for (int j = 0; j < 4; ++j)
          acc[i][j] = __builtin_amdgcn_mfma_f32_16x16x32_bf16(af[i], bfv[j],
                                                              acc[i][j], 0, 0, 0);
    }
    __syncthreads();
  }

  // epilogue: C/D layout col=lane&15, row=(lane>>4)*4+reg  [m89/m91 verified]
#pragma unroll
  for (int i = 0; i < 4; ++i) {
    const int mrow = m0 + mw + i * 16 + qd * 4;
#pragma unroll
    for (int j = 0; j < 4; ++j) {
      const int ncol = n0 + nw + j * 16 + li;
      const float bv = bias[ncol];
#pragma unroll
      for (int r = 0; r < 4; ++r) {
        const size_t off = (size_t)(mrow + r) * N + ncol;
        float v = acc[i][j][r] + bv;
        if (EPI == EPI_BIAS_RES) {
          out[off] = (bf16)(v + (float)R[off]);
        } else if (EPI == EPI_BIAS_GELU) {
          out[off] = (bf16)gelu_erf(v);
        } else {
          out[off] = (bf16)v;
        }
      }
    }
  }
}

// ---------------------------------------------------------------------------
// MFMA attention: one block (4 waves) per (sequence, head).
// P padded to PP (16-mult) for tiles; K-dim of PV padded to PK (32-mult).
// ---------------------------------------------------------------------------
template <int P>
__global__ __launch_bounds__(256) void attn_kernel(const bf16* __restrict__ qkv,
                                                   bf16* __restrict__ out) {
  constexpr int PP   = ((P + 15) / 16) * 16;   // 32, 48, 96
  constexpr int PK   = ((PP + 31) / 32) * 32;  // 32, 64, 96
  constexpr int MT   = PP / 16;
  constexpr int SSTR = PP + 2;                 // fp32 words
  constexpr int VSTR = PK + 8;                 // bf16 elems; *2B is 16B-mult
  constexpr int PSTR = PK + 8;

  __shared__ __align__(16) bf16 QK[2 * PP * 64];  // Q | K ; reused as Ps
  __shared__ __align__(16) bf16 Vt[64 * VSTR];
  __shared__ __align__(16) float Sm[PP * SSTR];
  __shared__ float rsum[PP];

  bf16* Qs = QK;
  bf16* Ks = QK + PP * 64;
  bf16* Ps = QK;  // overlays Q/K after S phase (dead by then)

  const int tid  = threadIdx.x;
  const int lane = tid & 63;
  const int wv   = tid >> 6;
  const int li   = lane & 15;
  const int qd   = lane >> 4;
  const int n    = blockIdx.x >> 3;
  const int h    = blockIdx.x & 7;
  const bf16* base = qkv + (size_t)n * P * QKV_D + h * 64;

  // stage Q,K: 16B chunks, slot = c ^ (r&7)
  for (int t = tid; t < P * 8; t += 256) {
    const int r = t >> 3, c = t & 7;
    const bf16x8 qv = *(const bf16x8*)(base + (size_t)r * QKV_D + c * 8);
    const bf16x8 kv = *(const bf16x8*)(base + (size_t)r * QKV_D + 512 + c * 8);
    *(bf16x8*)(Qs + r * 64 + ((c ^ (r & 7)) * 8)) = qv;
    *(bf16x8*)(Ks + r * 64 + ((c ^ (r & 7)) * 8)) = kv;
  }
  // stage V^T
  for (int t = tid; t < P * 8; t += 256) {
    const int j = t % P, dc = t / P;
    const bf16x8 vv = *(const bf16x8*)(base + (size_t)j * QKV_D + 1024 + dc * 8);
#pragma unroll
    for (int u = 0; u < 8; ++u) Vt[(dc * 8 + u) * VSTR + j] = vv[u];
  }
  if constexpr (PK > P) {
    for (int t = tid; t < 64 * (PK - P); t += 256) {
      const int d = t / (PK - P), j = P + t % (PK - P);
      Vt[d * VSTR + j] = (bf16)0.f;
    }
  }
  __syncthreads();

  // S = Q K^T
  for (int t = wv; t < MT * MT; t += 4) {
    const int ti = t / MT, tj = t % MT;
    f32x4 acc = (f32x4){0.f, 0.f, 0.f, 0.f};
#pragma unroll
    for (int ks = 0; ks < 2; ++ks) {
      const int ck = ks * 4 + qd;
      const int ar = ti * 16 + li;
      const int br = tj * 16 + li;
      const bf16x8 af = *(const bf16x8*)(Qs + ar * 64 + ((ck ^ (ar & 7)) * 8));
      const bf16x8 bv = *(const bf16x8*)(Ks + br * 64 + ((ck ^ (br & 7)) * 8));
      acc = __builtin_amdgcn_mfma_f32_16x16x32_bf16(af, bv, acc, 0, 0, 0);
    }
#pragma unroll
    for (int r = 0; r < 4; ++r)
      Sm[(ti * 16 + qd * 4 + r) * SSTR + tj * 16 + li] = acc[r];
  }
  __syncthreads();

  // softmax row: unnormalized exp -> bf16 Ps; 1/sum saved for O-write
  if (tid < P) {
    const float* srow = Sm + tid * SSTR;
    bf16* prow = Ps + tid * PSTR;
    float mx = -1e30f;
    for (int j = 0; j < P; ++j) mx = fmaxf(mx, srow[j]);
    mx *= 0.125f;  // 1/sqrt(64)
    float sum = 0.f;
    for (int j = 0; j < P; ++j) {
      const float e = __expf(srow[j] * 0.125f - mx);
      sum += e;
      prow[j] = (bf16)e;
    }
    for (int j = P; j < PK; ++j) prow[j] = (bf16)0.f;
    rsum[tid] = 1.f / sum;
  }
  __syncthreads();

  // O = P V
  for (int t = wv; t < MT * 4; t += 4) {
    const int ti = t >> 2, td = t & 3;
    f32x4 acc = (f32x4){0.f, 0.f, 0.f, 0.f};
#pragma unroll
    for (int ks = 0; ks < PK / 32; ++ks) {
      const int ck = ks * 4 + qd;
      const bf16x8 af = *(const bf16x8*)(Ps + (ti * 16 + li) * PSTR + ck * 8);
      const bf16x8 bv = *(const bf16x8*)(Vt + (td * 16 + li) * VSTR + ck * 8);
      acc = __builtin_amdgcn_mfma_f32_16x16x32_bf16(af, bv, acc, 0, 0, 0);
    }
#pragma unroll
    for (int r = 0; r < 4; ++r) {
      const int row = ti * 16 + qd * 4 + r;
      if (row < P)
        out[(size_t)(n * P + row) * HID + h * 64 + td * 16 + li] =
            (bf16)(acc[r] * rsum[row]);
    }
  }
}

// ---------------------------------------------------------------------------
// LayerNorm over 512, one wave per row. Y bf16 in (one b128/lane), bf16 out.
// ---------------------------------------------------------------------------
__global__ __launch_bounds__(256) void ln_kernel(const bf16* __restrict__ Y,
                                                 const float* __restrict__ w,
                                                 const float* __restrict__ b,
                                                 bf16* __restrict__ X) {
  const int row  = blockIdx.x * 4 + (threadIdx.x >> 6);
  const int lane = threadIdx.x & 63;
  const bf16x8 yv = *(const bf16x8*)(Y + (size_t)row * HID + 8 * lane);
  float v[8], s = 0.f, s2 = 0.f;
#pragma unroll
  for (int k = 0; k < 8; ++k) {
    v[k] = (float)yv[k];
    s += v[k];
    s2 += v[k] * v[k];
  }
#pragma unroll
  for (int off = 32; off > 0; off >>= 1) {
    s  += __shfl_xor(s, off, 64);
    s2 += __shfl_xor(s2, off, 64);
  }
  const float mean = s * (1.f / 512.f);
  const float var  = s2 * (1.f / 512.f) - mean * mean;
  const float rstd = rsqrtf(var + 1e-5f);
  const float4 w0 = ((const float4*)w)[2 * lane];
  const float4 w1 = ((const float4*)w)[2 * lane + 1];
  const float4 b0 = ((const float4*)b)[2 * lane];
  const float4 b1 = ((const float4*)b)[2 * lane + 1];
  bf16x8 o;
  o[0] = (bf16)((v[0] - mean) * rstd * w0.x + b0.x);
  o[1] = (bf16)((v[1] - mean) * rstd * w0.y + b0.y);
  o[2] = (bf16)((v[2] - mean) * rstd * w0.z + b0.z);
  o[3] = (bf16)((v[3] - mean) * rstd * w0.w + b0.w);
  o[4] = (bf16)((v[4] - mean) * rstd * w1.x + b1.x);
  o[5] = (bf16)((v[5] - mean) * rstd * w1.y + b1.y);
  o[6] = (bf16)((v[6] - mean) * rstd * w1.z + b1.z);
  o[7] = (bf16)((v[7] - mean) * rstd * w1.w + b1.w);
  *(bf16x8*)(X + (size_t)row * HID + 8 * lane) = o;
}

// ---------------------------------------------------------------------------
// input projection: h[r,o] = sum_k x[r,k]*w[o,k] + b[o], K=7. Writes the same
// value to nbr consecutive [TOKENS,HID] slices (branches share the input).
// ---------------------------------------------------------------------------
__global__ __launch_bounds__(256) void inproj_kernel(const float* __restrict__ x,
                                                     const float* __restrict__ w,
                                                     const float* __restrict__ b,
                                                     bf16* __restrict__ h,
                                                     int nbr) {
  const int idx = blockIdx.x * 256 + threadIdx.x;
  const int r = idx >> 9, o = idx & 511;
  float s = b[o];
#pragma unroll
  for (int k = 0; k < 7; ++k) s += x[r * 7 + k] * w[o * 7 + k];
  const bf16 bv = (bf16)s;
  for (int q = 0; q < nbr; ++q) h[idx + (size_t)q * TOKENS * HID] = bv;
}

// acc[row] (+)= X[row,:] . w  (per-branch final projection accumulate)
__global__ __launch_bounds__(256) void outdot_kernel(const bf16* __restrict__ X,
                                                     const float* __restrict__ w,
                                                     float* __restrict__ acc,
                                                     int first) {
  const int row  = blockIdx.x * 4 + (threadIdx.x >> 6);
  const int lane = threadIdx.x & 63;
  const bf16* xr = X + (size_t)row * HID;
  const bf16x8 xa = *(const bf16x8*)(xr + 8 * lane);
  const float4 wa = ((const float4*)w)[2 * lane];
  const float4 wb = ((const float4*)w)[2 * lane + 1];
  float s = (float)xa[0] * wa.x + (float)xa[1] * wa.y + (float)xa[2] * wa.z +
            (float)xa[3] * wa.w + (float)xa[4] * wb.x + (float)xa[5] * wb.y +
            (float)xa[6] * wb.z + (float)xa[7] * wb.w;
#pragma unroll
  for (int off = 32; off > 0; off >>= 1) s += __shfl_xor(s, off, 64);
  if (lane == 0) acc[row] = first ? s : (acc[row] + s);
}

// out[b,o] = (1/30) * sum_{j<10} acc[b*960 + o*10 + j] + b_out   (fp32 out)
__global__ __launch_bounds__(256) void pool_kernel(const float* __restrict__ acc,
                                                   const float* __restrict__ ob,
                                                   float* __restrict__ out) {
  const int idx = blockIdx.x * 256 + threadIdx.x;
  if (idx >= 16 * 96) return;
  const int bb = idx / 96, o = idx % 96;
  float s = 0.f;
#pragma unroll
  for (int j = 0; j < 10; ++j) s += acc[bb * 960 + o * 10 + j];
  out[idx] = s * (1.f / 30.f) + ob[0];
}

// ---------------------------------------------------------------------------
extern "C" void kernel_launch(void* const* d_in, const int* in_sizes, int n_in,
                              void* d_out, int out_size, void* d_ws,
                              size_t ws_size, hipStream_t stream) {
  const float* x          = (const float*)d_in[0];
  const float* ip_w       = (const float*)d_in[1];
  const float* ip_b       = (const float*)d_in[2];
  const float* in_proj_w  = (const float*)d_in[3];
  const float* in_proj_b  = (const float*)d_in[4];
  const float* out_proj_w = (const float*)d_in[5];
  const float* out_proj_b = (const float*)d_in[6];
  const float* ffn_w1     = (const float*)d_in[7];
  const float* ffn_b1     = (const float*)d_in[8];
  const float* ffn_w2     = (const float*)d_in[9];
  const float* ffn_b2     = (const float*)d_in[10];
  const float* ln1_w      = (const float*)d_in[11];
  const float* ln1_b      = (const float*)d_in[12];
  const float* ln2_w      = (const float*)d_in[13];
  const float* ln2_b      = (const float*)d_in[14];
  const float* op_w       = (const float*)d_in[15];
  const float* op_b       = (const float*)d_in[16];

  // fixed carve: weights + ACC, then activations (path-dependent)
  char* p = (char*)d_ws;
  bf16* Wq = (bf16*)p; p += (size_t)4 * QKV_D * HID * 2;
  bf16* Wo = (bf16*)p; p += (size_t)4 * HID * HID * 2;
  bf16* W1 = (bf16*)p; p += (size_t)4 * FFN_D * HID * 2;
  bf16* W2 = (bf16*)p; p += (size_t)4 * HID * FFN_D * 2;
  float* ACC = (float*)p; p += (size_t)TOKENS * 4;
  const size_t remain = ws_size - (size_t)(p - (char*)d_ws);

  const size_t T3 = 3 * (size_t)TOKENS;
  // per-token activation bytes: Y bf16 (1024) + X bf16 (1024) + SCR (4096)
  const size_t need_batched = T3 * 6144;                 // ~283 MB
  const size_t need_seq     = (size_t)TOKENS * 6144;     // ~94 MB
  const bool batched = remain >= need_batched;
  if (!batched && remain < need_seq) return;

  {  // weight conversion fp32 -> bf16
    const int nq = 4 * QKV_D * HID / 4, no = 4 * HID * HID / 4,
              n1 = 4 * FFN_D * HID / 4, n2 = 4 * HID * FFN_D / 4;
    cvt_kernel<<<(nq + 255) / 256, 256, 0, stream>>>(in_proj_w, Wq, nq);
    cvt_kernel<<<(no + 255) / 256, 256, 0, stream>>>(out_proj_w, Wo, no);
    cvt_kernel<<<(n1 + 255) / 256, 256, 0, stream>>>(ffn_w1, W1, n1);
    cvt_kernel<<<(n2 + 255) / 256, 256, 0, stream>>>(ffn_w2, W2, n2);
  }

  static const int periods[3] = {24, 48, 96};
  auto launch_attn = [&](int P, const bf16* q, bf16* o) {
    const int nblk = (TOKENS / P) * 8;
    if (P == 24)      attn_kernel<24><<<nblk, 256, 0, stream>>>(q, o);
    else if (P == 48) attn_kernel<48><<<nblk, 256, 0, stream>>>(q, o);
    else              attn_kernel<96><<<nblk, 256, 0, stream>>>(q, o);
  };

  const size_t TT = batched ? T3 : (size_t)TOKENS;
  bf16* Y   = (bf16*)p;  p += TT * HID * 2;
  bf16* X   = (bf16*)p;  p += TT * HID * 2;
  bf16* SCR = (bf16*)p;  p += TT * FFN_D * 2;
  bf16* ATT = SCR + TT * QKV_D;  // tail of SCR (qkv uses 1536 of 2048 cols)

  if (batched) {
    const int M = (int)T3, MB = M / 128;
    inproj_kernel<<<TOKENS * HID / 256, 256, 0, stream>>>(x, ip_w, ip_b, X, 3);
    for (int l = 0; l < 4; ++l) {
      gemm_bt<EPI_BIAS_BF16><<<dim3(MB, QKV_D / 128), 256, 0, stream>>>(
          X, Wq + (size_t)l * QKV_D * HID, in_proj_b + l * QKV_D, nullptr,
          SCR, M, QKV_D, HID);
      for (int br = 0; br < 3; ++br)
        launch_attn(periods[br], SCR + (size_t)br * TOKENS * QKV_D,
                    ATT + (size_t)br * TOKENS * HID);
      gemm_bt<EPI_BIAS_RES><<<dim3(MB, HID / 128), 256, 0, stream>>>(
          ATT, Wo + (size_t)l * HID * HID, out_proj_b + l * HID, X, Y,
          M, HID, HID);
      ln_kernel<<<M / 4, 256, 0, stream>>>(Y, ln1_w + l * HID, ln1_b + l * HID, X);
      gemm_bt<EPI_BIAS_GELU><<<dim3(MB, FFN_D / 128), 256, 0, stream>>>(
          X, W1 + (size_t)l * FFN_D * HID, ffn_b1 + l * FFN_D, nullptr,
          SCR, M, FFN_D, HID);
      gemm_bt<EPI_BIAS_RES><<<dim3(MB, HID / 128), 256, 0, stream>>>(
          SCR, W2 + (size_t)l * HID * FFN_D, ffn_b2 + l * HID, X, Y,
          M, HID, FFN_D);
      ln_kernel<<<M / 4, 256, 0, stream>>>(Y, ln2_w + l * HID, ln2_b + l * HID, X);
    }
    for (int br = 0; br < 3; ++br)
      outdot_kernel<<<TOKENS / 4, 256, 0, stream>>>(
          X + (size_t)br * TOKENS * HID, op_w, ACC, br == 0);
  } else {
    const int M = TOKENS, MB = M / 128;
    for (int br = 0; br < 3; ++br) {
      inproj_kernel<<<TOKENS * HID / 256, 256, 0, stream>>>(x, ip_w, ip_b, X, 1);
      for (int l = 0; l < 4; ++l) {
        gemm_bt<EPI_BIAS_BF16><<<dim3(MB, QKV_D / 128), 256, 0, stream>>>(
            X, Wq + (size_t)l * QKV_D * HID, in_proj_b + l * QKV_D, nullptr,
            SCR, M, QKV_D, HID);
        launch_attn(periods[br], SCR, ATT);
        gemm_bt<EPI_BIAS_RES><<<dim3(MB, HID / 128), 256, 0, stream>>>(
            ATT, Wo + (size_t)l * HID * HID, out_proj_b + l * HID, X, Y,
            M, HID, HID);
        ln_kernel<<<M / 4, 256, 0, stream>>>(Y, ln1_w + l * HID,
                                             ln1_b + l * HID, X);
        gemm_bt<EPI_BIAS_GELU><<<dim3(MB, FFN_D / 128), 256, 0, stream>>>(
            X, W1 + (size_t)l * FFN_D * HID, ffn_b1 + l * FFN_D, nullptr,
            SCR, M, FFN_D, HID);
        gemm_bt<EPI_BIAS_RES><<<dim3(MB, HID / 128), 256, 0, stream>>>(
            SCR, W2 + (size_t)l * HID * FFN_D, ffn_b2 + l * HID, X, Y,
            M, HID, FFN_D);
        ln_kernel<<<M / 4, 256, 0, stream>>>(Y, ln2_w + l * HID,
                                             ln2_b + l * HID, X);
      }
      outdot_kernel<<<TOKENS / 4, 256, 0, stream>>>(X, op_w, ACC, br == 0);
    }
  }
  pool_kernel<<<6, 256, 0, stream>>>(ACC, op_b, (float*)d_out);
}